// Round 3
// baseline (366.442 us; speedup 1.0000x reference)
//
#include <hip/hip_runtime.h>

// IntensityTransformation: out_k[b,c,h,w] = tf_k[b,c, round(255*img[b,c,h,w])]
// B=8, C=3, H=W=1024, LUT=256. Memory-bound LUT gather.
//
// R2: same as R1 (4 float4/thread, merged float4 LDS LUT, nontemporal
// global traffic) but using clang native vector type for the nontemporal
// builtins (HIP_vector_type float4 is rejected by the builtin).

typedef float vfloat4 __attribute__((ext_vector_type(4)));

#define PLANES 24                     // B*C
#define PLANE_PIX (1024 * 1024)
#define VEC4_PER_PLANE (PLANE_PIX / 4)                  // 262144
#define BLOCK 256
#define PER_THREAD 4
#define BLOCKS_PER_PLANE (VEC4_PER_PLANE / (BLOCK * PER_THREAD))  // 256
#define TOTAL_VEC4 (PLANES * VEC4_PER_PLANE)            // 6291456

__global__ __launch_bounds__(BLOCK) void intensity_lut_kernel(
    const vfloat4* __restrict__ img,
    const float*  __restrict__ tf1,
    const float*  __restrict__ tf2,
    const float*  __restrict__ tf3,
    vfloat4* __restrict__ out)
{
    // Merged LUT: lut[i] = {tf1[i], tf2[i], tf3[i], 0}  -> one b128 per pixel
    __shared__ vfloat4 lut[256];

    const int plane = blockIdx.y;      // 0..23
    const int t = threadIdx.x;         // 0..255

    {
        vfloat4 e;
        e.x = tf1[plane * 256 + t];
        e.y = tf2[plane * 256 + t];
        e.z = tf3[plane * 256 + t];
        e.w = 0.0f;
        lut[t] = e;
    }
    __syncthreads();

    const long long base = (long long)plane * VEC4_PER_PLANE
                         + (long long)blockIdx.x * (BLOCK * PER_THREAD) + t;

    // Issue all 4 independent img loads first (ILP / latency hiding).
    vfloat4 v[PER_THREAD];
#pragma unroll
    for (int j = 0; j < PER_THREAD; ++j)
        v[j] = __builtin_nontemporal_load(&img[base + (long long)j * BLOCK]);

#pragma unroll
    for (int j = 0; j < PER_THREAD; ++j) {
        // jnp.round is round-half-to-even; __float2int_rn matches.
        int i0 = __float2int_rn(255.0f * v[j].x);
        int i1 = __float2int_rn(255.0f * v[j].y);
        int i2 = __float2int_rn(255.0f * v[j].z);
        int i3 = __float2int_rn(255.0f * v[j].w);
        i0 = min(max(i0, 0), 255);
        i1 = min(max(i1, 0), 255);
        i2 = min(max(i2, 0), 255);
        i3 = min(max(i3, 0), 255);

        vfloat4 e0 = lut[i0];
        vfloat4 e1 = lut[i1];
        vfloat4 e2 = lut[i2];
        vfloat4 e3 = lut[i3];

        vfloat4 o1 = { e0.x, e1.x, e2.x, e3.x };
        vfloat4 o2 = { e0.y, e1.y, e2.y, e3.y };
        vfloat4 o3 = { e0.z, e1.z, e2.z, e3.z };

        const long long i = base + (long long)j * BLOCK;
        __builtin_nontemporal_store(o1, &out[i]);
        __builtin_nontemporal_store(o2, &out[i + TOTAL_VEC4]);
        __builtin_nontemporal_store(o3, &out[i + 2LL * TOTAL_VEC4]);
    }
}

extern "C" void kernel_launch(void* const* d_in, const int* in_sizes, int n_in,
                              void* d_out, int out_size, void* d_ws, size_t ws_size,
                              hipStream_t stream) {
    const vfloat4* img = (const vfloat4*)d_in[0];
    const float*  tf1 = (const float*)d_in[1];
    const float*  tf2 = (const float*)d_in[2];
    const float*  tf3 = (const float*)d_in[3];
    vfloat4* out = (vfloat4*)d_out;

    dim3 grid(BLOCKS_PER_PLANE, PLANES);
    dim3 block(BLOCK);
    intensity_lut_kernel<<<grid, block, 0, stream>>>(img, tf1, tf2, tf3, out);
}